// Round 4
// baseline (154.020 us; speedup 1.0000x reference)
//
#include <hip/hip_runtime.h>

typedef float f32x4 __attribute__((ext_vector_type(4)));
typedef short bf16x8 __attribute__((ext_vector_type(8)));

__device__ __forceinline__ short f2bf(float f) {
    union { float f; unsigned u; } c; c.f = f;
    unsigned r = (c.u + 0x7fffu + ((c.u >> 16) & 1u)) >> 16;
    return (short)r;
}

// ---------------- v2 geometry ----------------
#define BM 32           // batch rows per block
#define XT_S 296        // shorts, x-feature tile stride (288 used + pad)
#define AY_S 136        // shorts, stride of state-stage / y tile (128 + pad)
#define ZL_S 68         // floats, z tile stride
#define LDS2_BYTES 28160

// ws layout (shorts): Dext frags | W1 frags | W2 frags
#define DEXT_SHORTS (18*4*512)   // 36864: 18 n-tiles x 4 k-chunks
#define W1_SHORTS   (99*512)     // 50688: 11 n-tiles x 9 k-chunks
#define W2_SHORTS   (16*512)     // 8192:  4 n-tiles x 4 k-chunks
#define WS2_SHORTS  (DEXT_SHORTS + W1_SHORTS + W2_SHORTS)   // 95744 (191488 B)

__device__ __forceinline__ int m8(int x, int y) {
    constexpr int M8[8][8] = {
        {0,1,2,3,3,2,1,0},{1,4,5,6,6,5,4,1},{2,5,7,8,8,7,5,2},{3,6,8,9,9,8,6,3},
        {3,6,8,9,9,8,6,3},{2,5,7,8,8,7,5,2},{1,4,5,6,6,5,4,1},{0,1,2,3,3,2,1,0}};
    return M8[x][y];
}

// ---- one-time: params/weights -> bf16 MFMA fragment layout in ws ----
__global__ __launch_bounds__(256) void prep2(
    const float* __restrict__ myp,  const float* __restrict__ hisp,
    const float* __restrict__ w1a,  const float* __restrict__ w1v,
    const float* __restrict__ w2a,  short* __restrict__ ws)
{
    int i = blockIdx.x * 256 + threadIdx.x;
    if (i >= WS2_SHORTS) return;
    float v = 0.f;
    if (i < DEXT_SHORTS) {
        int e = i & 7, lane = (i >> 3) & 63, tc = i >> 9;   // tc = nt*4+kc
        int nt = tc >> 2, kc = tc & 3;
        int n = nt * 16 + (lane & 15);
        int k = kc * 32 + (lane >> 4) * 8 + e;              // 0..127
        int p = k >> 6, cell = k & 63, x = cell >> 3, y = cell & 7;
        const float* pr = p ? hisp : myp;
        if (n < 276) {
            bool match = false; int j = 0;
            if (n < 48)       { int p2 = n & 1, t = n >> 1; j = t >> 3; match = (p2 == p) && ((t & 7) == x); }
            else if (n < 96)  { int m = n - 48, p2 = m & 1, t = m >> 1; j = t >> 3; match = (p2 == p) && ((t & 7) == y); }
            else if (n < 186) { int m = n - 96, p2 = m & 1, t = m >> 1; j = t / 15;
                                match = (p2 == p) && ((t % 15) == ((y >= x) ? (y - x) : (x - y + 7))); }
            else              { int m = n - 186, p2 = m & 1, t = m >> 1; j = t / 15;
                                match = (p2 == p) && ((t % 15) == (x + y)); }
            if (match) v = pr[j * 10 + m8(x, y)];
        }
    } else if (i < DEXT_SHORTS + W1_SHORTS) {
        int ii = i - DEXT_SHORTS;
        int e = ii & 7, lane = (ii >> 3) & 63, tc = ii >> 9; // tc = nt*9+kc
        int nt = tc / 9, kc = tc % 9;
        int n = nt * 16 + (lane & 15);
        int k = kc * 32 + (lane >> 4) * 8 + e;
        if (k < 276) {
            if (n < 100)                  v = w1a[n * 276 + k];
            else if (n >= 112 && n < 176) v = w1v[(n - 112) * 276 + k];
        }
    } else {
        int ii = i - DEXT_SHORTS - W1_SHORTS;
        int e = ii & 7, lane = (ii >> 3) & 63, tc = ii >> 9; // tc = nt*4+kc
        int n = (tc >> 2) * 16 + (lane & 15);
        int k = (tc & 3) * 32 + (lane >> 4) * 8 + e;
        if (k < 100) v = w2a[n * 100 + k];
    }
    ws[i] = f2bf(v);
}

// ---- main fused kernel: 32 batch rows per block ----
__global__ __launch_bounds__(384) void net_v2(
    const float* __restrict__ state,
    const float* __restrict__ b1a, const float* __restrict__ b2a,
    const float* __restrict__ b1v, const float* __restrict__ w2v,
    const float* __restrict__ b2v,
    const short* __restrict__ ws, float* __restrict__ out, int Btot)
{
    __shared__ __align__(16) unsigned char smem[LDS2_BYTES];
    short* xt   = (short*)smem;                 // [32][296] bf16 features (ph1->2)
    float* zl   = (float*)smem;                 // [32][68] f32 logits (ph3->4, aliases xt)
    short* ay   = (short*)(smem + 18944);       // [32][136]: state-stage (ph0->1), then y (ph2->3)
    float* valp = (float*)(smem + 27648);       // [4][32] val partials

    const int tid  = threadIdx.x;
    const int w    = tid >> 6;      // wave 0..5
    const int l    = tid & 63;
    const int lrow = l & 15;
    const int lk   = l >> 4;
    const int bg0  = blockIdx.x * BM;

    // ---- phase 0: stage state rows -> ay as bf16, coalesced ----
    {
        const float* sp = state + (size_t)bg0 * 128;
        #pragma unroll
        for (int it = 0; it < 3; ++it) {
            int t = tid + it * 384;             // float4 index, need < 1024
            if (t < 1024) {
                f32x4 v4 = *(const f32x4*)(sp + t * 4);
                int f = t * 4, row = f >> 7, col = f & 127;
                short* dst = ay + row * AY_S + col;
                dst[0] = f2bf(v4[0]); dst[1] = f2bf(v4[1]);
                dst[2] = f2bf(v4[2]); dst[3] = f2bf(v4[3]);
            }
        }
    }
    // conv B-frags (Dext), needed right after barrier
    bf16x8 dx[3][4];
    #pragma unroll
    for (int ni = 0; ni < 3; ni++) {
        const int nt = w + ni * 6;
        #pragma unroll
        for (int kc = 0; kc < 4; kc++)
            dx[ni][kc] = *(const bf16x8*)(ws + ((nt * 4 + kc) * 64 + l) * 8);
    }
    __syncthreads();

    // ---- phase 1: conv-GEMM  S[32,128] @ Dext[128,288] -> relu -> xt ----
    {
        f32x4 ca[2][3];
        #pragma unroll
        for (int mt = 0; mt < 2; mt++)
            #pragma unroll
            for (int ni = 0; ni < 3; ni++) ca[mt][ni] = (f32x4){0.f,0.f,0.f,0.f};
        #pragma unroll
        for (int mt = 0; mt < 2; mt++) {
            bf16x8 a[4];
            #pragma unroll
            for (int kc = 0; kc < 4; kc++)
                a[kc] = *(const bf16x8*)(ay + (mt * 16 + lrow) * AY_S + kc * 32 + lk * 8);
            #pragma unroll
            for (int ni = 0; ni < 3; ni++)
                #pragma unroll
                for (int kc = 0; kc < 4; kc++)
                    ca[mt][ni] = __builtin_amdgcn_mfma_f32_16x16x32_bf16(a[kc], dx[ni][kc], ca[mt][ni], 0, 0, 0);
        }
        #pragma unroll
        for (int mt = 0; mt < 2; mt++)
            #pragma unroll
            for (int ni = 0; ni < 3; ni++) {
                const int nt = w + ni * 6;
                #pragma unroll
                for (int r = 0; r < 4; r++)
                    xt[(mt * 16 + lk * 4 + r) * XT_S + nt * 16 + lrow] = f2bf(fmaxf(ca[mt][ni][r], 0.f));
            }
    }
    // GEMM1 B-frags + epilogue constants (loads overlap the barrier)
    const int nnt = (w < 5) ? 2 : 1;
    const int ntA[2] = { w, w + 6 };
    bf16x8 bf[2][9];
    for (int ni = 0; ni < nnt; ni++)
        #pragma unroll
        for (int kc = 0; kc < 9; kc++)
            bf[ni][kc] = *(const bf16x8*)(ws + DEXT_SHORTS + ((ntA[ni] * 9 + kc) * 64 + l) * 8);
    float ep_bias[2] = {0.f, 0.f}, ep_wv[2] = {0.f, 0.f};
    for (int ni = 0; ni < nnt; ni++) {
        const int col = ntA[ni] * 16 + lrow;
        if (ntA[ni] <= 6) ep_bias[ni] = (col < 100) ? b1a[col] : 0.f;
        else { ep_bias[ni] = b1v[col - 112]; ep_wv[ni] = w2v[col - 112]; }
    }
    __syncthreads();

    // ---- phase 2: GEMM1  x[32,288] @ W1[288,176] ----
    {
        f32x4 acc[2][2];
        #pragma unroll
        for (int ni = 0; ni < 2; ni++)
            #pragma unroll
            for (int mt = 0; mt < 2; mt++) acc[ni][mt] = (f32x4){0.f,0.f,0.f,0.f};
        #pragma unroll
        for (int mt = 0; mt < 2; mt++) {
            bf16x8 a[9];
            #pragma unroll
            for (int kc = 0; kc < 9; kc++)
                a[kc] = *(const bf16x8*)(xt + (mt * 16 + lrow) * XT_S + kc * 32 + lk * 8);
            for (int ni = 0; ni < nnt; ni++)
                #pragma unroll
                for (int kc = 0; kc < 9; kc++)
                    acc[ni][mt] = __builtin_amdgcn_mfma_f32_16x16x32_bf16(a[kc], bf[ni][kc], acc[ni][mt], 0, 0, 0);
        }
        // epilogue: act -> ay (y tile); val -> reduce -> valp
        for (int ni = 0; ni < nnt; ni++) {
            const int nt = ntA[ni];
            if (nt <= 6) {
                #pragma unroll
                for (int mt = 0; mt < 2; mt++)
                    #pragma unroll
                    for (int r = 0; r < 4; r++) {
                        float v = fmaxf(acc[ni][mt][r] + ep_bias[ni], 0.f);
                        ay[(mt * 16 + lk * 4 + r) * AY_S + nt * 16 + lrow] = f2bf(v);
                    }
                if (nt == 6) {      // zero y cols 112..127 (K-pad for GEMM2)
                    #pragma unroll
                    for (int mt = 0; mt < 2; mt++)
                        #pragma unroll
                        for (int r = 0; r < 4; r++)
                            ay[(mt * 16 + lk * 4 + r) * AY_S + 112 + lrow] = 0;
                }
            } else {
                #pragma unroll
                for (int mt = 0; mt < 2; mt++)
                    #pragma unroll
                    for (int r = 0; r < 4; r++) {
                        float v = fmaxf(acc[ni][mt][r] + ep_bias[ni], 0.f) * ep_wv[ni];
                        v += __shfl_xor(v, 1); v += __shfl_xor(v, 2);
                        v += __shfl_xor(v, 4); v += __shfl_xor(v, 8);
                        if (lrow == 0) valp[(nt - 7) * 32 + mt * 16 + lk * 4 + r] = v;
                    }
            }
        }
    }
    // GEMM2 B-frags
    bf16x8 b2f[4];
    float bias2 = 0.f;
    if (w < 4) {
        #pragma unroll
        for (int kc = 0; kc < 4; kc++)
            b2f[kc] = *(const bf16x8*)(ws + DEXT_SHORTS + W1_SHORTS + ((w * 4 + kc) * 64 + l) * 8);
        bias2 = b2a[w * 16 + lrow];
    }
    __syncthreads();

    // ---- phase 3: GEMM2 (waves 0-3) -> zl; wave 4: tanh(val) ----
    if (w < 4) {
        f32x4 acc2[2];
        #pragma unroll
        for (int mt = 0; mt < 2; mt++) acc2[mt] = (f32x4){0.f,0.f,0.f,0.f};
        #pragma unroll
        for (int mt = 0; mt < 2; mt++)
            #pragma unroll
            for (int kc = 0; kc < 4; kc++) {
                bf16x8 a2 = *(const bf16x8*)(ay + (mt * 16 + lrow) * AY_S + kc * 32 + lk * 8);
                acc2[mt] = __builtin_amdgcn_mfma_f32_16x16x32_bf16(a2, b2f[kc], acc2[mt], 0, 0, 0);
            }
        #pragma unroll
        for (int mt = 0; mt < 2; mt++)
            #pragma unroll
            for (int r = 0; r < 4; r++)
                zl[(mt * 16 + lk * 4 + r) * ZL_S + w * 16 + lrow] = acc2[mt][r] + bias2;
    } else if (w == 4 && l < 32) {
        float v = valp[l] + valp[32 + l] + valp[64 + l] + valp[96 + l] + b2v[0];
        out[(size_t)Btot * 64 + bg0 + l] = tanhf(v);
    }
    __syncthreads();

    // ---- phase 4: log-softmax; full-line coalesced stores ----
    if (w < 4) {
        const int rl = l >> 3, q = l & 7;
        const int row = w * 8 + rl;
        const float* zr = zl + row * ZL_S + q * 8;
        f32x4 v0 = *(const f32x4*)(zr);
        f32x4 v1 = *(const f32x4*)(zr + 4);
        float m = fmaxf(fmaxf(fmaxf(v0[0], v0[1]), fmaxf(v0[2], v0[3])),
                        fmaxf(fmaxf(v1[0], v1[1]), fmaxf(v1[2], v1[3])));
        m = fmaxf(m, __shfl_xor(m, 1));
        m = fmaxf(m, __shfl_xor(m, 2));
        m = fmaxf(m, __shfl_xor(m, 4));
        float s = 0.f;
        #pragma unroll
        for (int e = 0; e < 4; e++) s += __expf(v0[e] - m);
        #pragma unroll
        for (int e = 0; e < 4; e++) s += __expf(v1[e] - m);
        s += __shfl_xor(s, 1);
        s += __shfl_xor(s, 2);
        s += __shfl_xor(s, 4);
        const float lsm = m + __logf(s);
        // stores: instr i writes 4 full rows x 256B contiguous
        #pragma unroll
        for (int i = 0; i < 2; i++) {
            const int rloc  = i * 4 + (l >> 4);      // 0..7
            const int row_s = w * 8 + rloc;
            const float lz  = __shfl(lsm, rloc * 8);
            f32x4 zv = *(const f32x4*)(zl + row_s * ZL_S + (l & 15) * 4);
            f32x4 ov;
            #pragma unroll
            for (int e = 0; e < 4; e++) ov[e] = zv[e] - lz;
            *(f32x4*)(out + (size_t)(bg0 + row_s) * 64 + (l & 15) * 4) = ov;
        }
    }
}

// ================= fallback (ws too small): R3 kernel, in-kernel weights =================
__global__ __launch_bounds__(384) void net_v1(
    const float* __restrict__ state,
    const float* __restrict__ myp,  const float* __restrict__ hisp,
    const float* __restrict__ w1a,  const float* __restrict__ b1a,
    const float* __restrict__ w2a,  const float* __restrict__ b2a,
    const float* __restrict__ w1v,  const float* __restrict__ b1v,
    const float* __restrict__ w2v,  const float* __restrict__ b2v,
    float* __restrict__ out, int Btot)
{
    __shared__ __align__(16) unsigned char smem[56320];
    short* xt   = (short*)smem;                 // [64][296]
    float* zl   = (float*)smem;                 // [64][68] aliases xt
    short* yl   = (short*)(smem + 37888);       // [64][136]
    float* valp = (float*)(smem + 55296);       // [4][64]
    const int tid = threadIdx.x, w = tid >> 6, l = tid & 63, lrow = l & 15, lk = l >> 4;
    for (int i = tid; i < 13824; i += 384) ((unsigned*)smem)[i] = 0u;
    const int nnt = (w < 5) ? 2 : 1;
    const int ntArr[2] = { w, w + 6 };
    bf16x8 bf[2][9];
    for (int ni = 0; ni < nnt; ni++) {
        const int n = ntArr[ni] * 16 + lrow;
        const float* src; bool valid;
        if (n < 100)       { src = w1a + (size_t)n * 276;         valid = true;  }
        else if (n >= 112) { src = w1v + (size_t)(n - 112) * 276; valid = true;  }
        else               { src = w1a;                           valid = false; }
        #pragma unroll
        for (int kc = 0; kc < 9; kc++) {
            bf16x8 r;
            #pragma unroll
            for (int e = 0; e < 8; e++) {
                int k = kc * 32 + lk * 8 + e;
                bool ok = valid && (k < 276);
                r[e] = f2bf(ok ? src[ok ? k : 0] : 0.f);
            }
            bf[ni][kc] = r;
        }
    }
    bf16x8 b2f[4]; float bias2 = 0.f;
    if (w < 4) {
        const float* src2 = w2a + (size_t)(w * 16 + lrow) * 100;
        #pragma unroll
        for (int kc = 0; kc < 4; kc++) {
            bf16x8 r;
            #pragma unroll
            for (int e = 0; e < 8; e++) { int k = kc * 32 + lk * 8 + e; r[e] = f2bf((k < 100) ? src2[k] : 0.f); }
            b2f[kc] = r;
        }
        bias2 = b2a[w * 16 + lrow];
    }
    float ep_bias[2] = {0.f,0.f}, ep_wv[2] = {0.f,0.f};
    for (int ni = 0; ni < nnt; ni++) {
        const int col = ntArr[ni] * 16 + lrow;
        if (ntArr[ni] <= 6) ep_bias[ni] = (col < 100) ? b1a[col] : 0.f;
        else { ep_bias[ni] = b1v[col - 112]; ep_wv[ni] = w2v[col - 112]; }
    }
    const float b2v0 = b2v[0];
    const int cp = (w >= 3) ? 1 : 0, cj = (w >= 3) ? (w - 3) : w;
    float prm[10];
    { const float* ps = (cp == 0 ? myp : hisp) + cj * 10;
      #pragma unroll
      for (int i = 0; i < 10; i++) prm[i] = ps[i]; }
    __syncthreads();
    for (int g = 0; g < 2; ++g) {
        const int bg0 = (blockIdx.x * 2 + g) * 64;
        if (bg0 >= Btot) break;
        {
            float racc[8], cacc[8], macc[15], aacc[15];
            #pragma unroll
            for (int i = 0; i < 8; i++) { racc[i] = 0.f; cacc[i] = 0.f; }
            #pragma unroll
            for (int i = 0; i < 15; i++) { macc[i] = 0.f; aacc[i] = 0.f; }
            const float* S = state + ((size_t)(bg0 + l) * 2 + cp) * 64;
            #pragma unroll
            for (int x = 0; x < 8; x++) {
                f32x4 lo = *(const f32x4*)(S + x * 8);
                f32x4 hi = *(const f32x4*)(S + x * 8 + 4);
                #pragma unroll
                for (int y = 0; y < 8; y++) {
                    float s = (y < 4) ? lo[y] : hi[y - 4];
                    float t = s * prm[m8(x, y)];
                    racc[x] += t; cacc[y] += t;
                    macc[(y >= x) ? (y - x) : (x - y + 7)] += t;
                    aacc[x + y] += t;
                }
            }
            short* xr = xt + l * XT_S;
            if (w == 0) { unsigned* xp = (unsigned*)(xr + 276);
                xp[0]=0u; xp[1]=0u; xp[2]=0u; xp[3]=0u; xp[4]=0u; xp[5]=0u; }
            #pragma unroll
            for (int i = 0; i < 8; i++)  xr[(cj * 8 + i) * 2 + cp]        = f2bf(fmaxf(racc[i], 0.f));
            #pragma unroll
            for (int i = 0; i < 8; i++)  xr[48 + (cj * 8 + i) * 2 + cp]   = f2bf(fmaxf(cacc[i], 0.f));
            #pragma unroll
            for (int k = 0; k < 15; k++) xr[96 + (cj * 15 + k) * 2 + cp]  = f2bf(fmaxf(macc[k], 0.f));
            #pragma unroll
            for (int k = 0; k < 15; k++) xr[186 + (cj * 15 + k) * 2 + cp] = f2bf(fmaxf(aacc[k], 0.f));
        }
        __syncthreads();
        f32x4 acc[2][4];
        #pragma unroll
        for (int ni = 0; ni < 2; ni++)
            #pragma unroll
            for (int mt = 0; mt < 4; mt++) acc[ni][mt] = (f32x4){0.f,0.f,0.f,0.f};
        for (int mt = 0; mt < 4; mt++) {
            bf16x8 a[9];
            #pragma unroll
            for (int kc = 0; kc < 9; kc++)
                a[kc] = *(const bf16x8*)(xt + (mt * 16 + lrow) * XT_S + kc * 32 + lk * 8);
            for (int ni = 0; ni < nnt; ni++)
                #pragma unroll
                for (int kc = 0; kc < 9; kc++)
                    acc[ni][mt] = __builtin_amdgcn_mfma_f32_16x16x32_bf16(a[kc], bf[ni][kc], acc[ni][mt], 0, 0, 0);
        }
        for (int ni = 0; ni < nnt; ni++) {
            const int nt = ntArr[ni];
            if (nt <= 6) {
                #pragma unroll
                for (int mt = 0; mt < 4; mt++)
                    #pragma unroll
                    for (int r = 0; r < 4; r++) {
                        float v = fmaxf(acc[ni][mt][r] + ep_bias[ni], 0.f);
                        yl[(mt * 16 + lk * 4 + r) * AY_S + nt * 16 + lrow] = f2bf(v);
                    }
            } else {
                #pragma unroll
                for (int mt = 0; mt < 4; mt++)
                    #pragma unroll
                    for (int r = 0; r < 4; r++) {
                        float v = fmaxf(acc[ni][mt][r] + ep_bias[ni], 0.f) * ep_wv[ni];
                        v += __shfl_xor(v, 1); v += __shfl_xor(v, 2);
                        v += __shfl_xor(v, 4); v += __shfl_xor(v, 8);
                        if (lrow == 0) valp[(nt - 7) * 64 + mt * 16 + lk * 4 + r] = v;
                    }
            }
        }
        __syncthreads();
        if (w < 4) {
            f32x4 acc2[4];
            #pragma unroll
            for (int mt = 0; mt < 4; mt++) acc2[mt] = (f32x4){0.f,0.f,0.f,0.f};
            #pragma unroll
            for (int mt = 0; mt < 4; mt++)
                #pragma unroll
                for (int kc = 0; kc < 4; kc++) {
                    bf16x8 a2 = *(const bf16x8*)(yl + (mt * 16 + lrow) * AY_S + kc * 32 + lk * 8);
                    acc2[mt] = __builtin_amdgcn_mfma_f32_16x16x32_bf16(a2, b2f[kc], acc2[mt], 0, 0, 0);
                }
            #pragma unroll
            for (int mt = 0; mt < 4; mt++)
                #pragma unroll
                for (int r = 0; r < 4; r++)
                    zl[(mt * 16 + lk * 4 + r) * ZL_S + w * 16 + lrow] = acc2[mt][r] + bias2;
        } else if (w == 4) {
            float v = valp[l] + valp[64 + l] + valp[128 + l] + valp[192 + l] + b2v0;
            out[(size_t)Btot * 64 + bg0 + l] = tanhf(v);
        }
        __syncthreads();
        if (w < 4) {
            const int rl = l >> 2, q = l & 3;
            const int row = w * 16 + rl;
            const float* zr = zl + row * ZL_S;
            f32x4 v[4]; float m = -1e30f;
            #pragma unroll
            for (int c = 0; c < 4; c++) {
                v[c] = *(const f32x4*)(zr + c * 16 + q * 4);
                m = fmaxf(m, fmaxf(fmaxf(v[c][0], v[c][1]), fmaxf(v[c][2], v[c][3])));
            }
            m = fmaxf(m, __shfl_xor(m, 1));
            m = fmaxf(m, __shfl_xor(m, 2));
            float s = 0.f;
            #pragma unroll
            for (int c = 0; c < 4; c++)
                #pragma unroll
                for (int e = 0; e < 4; e++) s += __expf(v[c][e] - m);
            s += __shfl_xor(s, 1);
            s += __shfl_xor(s, 2);
            const float lsm = m + __logf(s);
            float* o = out + (size_t)(bg0 + row) * 64;
            #pragma unroll
            for (int c = 0; c < 4; c++) {
                f32x4 ov;
                #pragma unroll
                for (int e = 0; e < 4; e++) ov[e] = v[c][e] - lsm;
                *(f32x4*)(o + c * 16 + q * 4) = ov;
            }
        }
        __syncthreads();
    }
}

extern "C" void kernel_launch(void* const* d_in, const int* in_sizes, int n_in,
                              void* d_out, int out_size, void* d_ws, size_t ws_size,
                              hipStream_t stream) {
    const float* state = (const float*)d_in[0];
    const float* myp   = (const float*)d_in[1];
    const float* hisp  = (const float*)d_in[2];
    const float* w1a   = (const float*)d_in[3];
    const float* b1a   = (const float*)d_in[4];
    const float* w2a   = (const float*)d_in[5];
    const float* b2a   = (const float*)d_in[6];
    const float* w1v   = (const float*)d_in[7];
    const float* b1v   = (const float*)d_in[8];
    const float* w2v   = (const float*)d_in[9];
    const float* b2v   = (const float*)d_in[10];
    float* out = (float*)d_out;
    const int Btot = in_sizes[0] / 128;          // (B,2,8,8)
    if (ws_size >= (size_t)WS2_SHORTS * sizeof(short)) {
        short* ws = (short*)d_ws;
        prep2<<<dim3((WS2_SHORTS + 255) / 256), dim3(256), 0, stream>>>(myp, hisp, w1a, w1v, w2a, ws);
        net_v2<<<dim3(Btot / BM), dim3(384), 0, stream>>>(
            state, b1a, b2a, b1v, w2v, b2v, ws, out, Btot);
    } else {
        net_v1<<<dim3((Btot + 127) / 128), dim3(384), 0, stream>>>(
            state, myp, hisp, w1a, b1a, w2a, b2a, w1v, b1v, w2v, b2v, out, Btot);
    }
}

// Round 8
// 46.189 us; speedup vs baseline: 3.3346x; 3.3346x over previous
//
#include <hip/hip_runtime.h>

typedef float f32x4 __attribute__((ext_vector_type(4)));
typedef short bf16x8 __attribute__((ext_vector_type(8)));

__device__ __forceinline__ short f2bf(float f) {
    union { float f; unsigned u; } c; c.f = f;
    unsigned r = (c.u + 0x7fffu + ((c.u >> 16) & 1u)) >> 16;
    return (short)r;
}

#define XT_S 296        // shorts, x-feature tile stride (288 used + pad), 16B-aligned rows
#define AY_S 136        // shorts, state-stage / y tile stride (128 + pad), 16B-aligned rows
#define ZL_S 68         // floats, z tile stride

// ws layout (shorts): Dext frags | W1 frags | W2 frags  (identical to R4's validated prep)
#define DEXT_SHORTS (18*4*512)   // 18 n-tiles x 4 k-chunks
#define W1_SHORTS   (99*512)     // 11 n-tiles x 9 k-chunks
#define W2_SHORTS   (16*512)     // 4 n-tiles x 4 k-chunks
#define WS2_SHORTS  (DEXT_SHORTS + W1_SHORTS + W2_SHORTS)   // 95744 shorts = 191488 B

__device__ __forceinline__ int m8(int x, int y) {
    constexpr int M8[8][8] = {
        {0,1,2,3,3,2,1,0},{1,4,5,6,6,5,4,1},{2,5,7,8,8,7,5,2},{3,6,8,9,9,8,6,3},
        {3,6,8,9,9,8,6,3},{2,5,7,8,8,7,5,2},{1,4,5,6,6,5,4,1},{0,1,2,3,3,2,1,0}};
    return M8[x][y];
}

// ---- one-time: params/weights -> bf16 MFMA fragment layout in ws (validated R4) ----
__global__ __launch_bounds__(256) void prep2(
    const float* __restrict__ myp,  const float* __restrict__ hisp,
    const float* __restrict__ w1a,  const float* __restrict__ w1v,
    const float* __restrict__ w2a,  short* __restrict__ ws)
{
    int i = blockIdx.x * 256 + threadIdx.x;
    if (i >= WS2_SHORTS) return;
    float v = 0.f;
    if (i < DEXT_SHORTS) {
        int e = i & 7, lane = (i >> 3) & 63, tc = i >> 9;   // tc = nt*4+kc
        int nt = tc >> 2, kc = tc & 3;
        int n = nt * 16 + (lane & 15);
        int k = kc * 32 + (lane >> 4) * 8 + e;              // 0..127
        int p = k >> 6, cell = k & 63, x = cell >> 3, y = cell & 7;
        const float* pr = p ? hisp : myp;
        if (n < 276) {
            bool match = false; int j = 0;
            if (n < 48)       { int p2 = n & 1, t = n >> 1; j = t >> 3; match = (p2 == p) && ((t & 7) == x); }
            else if (n < 96)  { int m = n - 48, p2 = m & 1, t = m >> 1; j = t >> 3; match = (p2 == p) && ((t & 7) == y); }
            else if (n < 186) { int m = n - 96, p2 = m & 1, t = m >> 1; j = t / 15;
                                match = (p2 == p) && ((t % 15) == ((y >= x) ? (y - x) : (x - y + 7))); }
            else              { int m = n - 186, p2 = m & 1, t = m >> 1; j = t / 15;
                                match = (p2 == p) && ((t % 15) == (x + y)); }
            if (match) v = pr[j * 10 + m8(x, y)];
        }
    } else if (i < DEXT_SHORTS + W1_SHORTS) {
        int ii = i - DEXT_SHORTS;
        int e = ii & 7, lane = (ii >> 3) & 63, tc = ii >> 9; // tc = nt*9+kc
        int nt = tc / 9, kc = tc % 9;
        int n = nt * 16 + (lane & 15);
        int k = kc * 32 + (lane >> 4) * 8 + e;
        if (k < 276) {
            if (n < 100)                  v = w1a[n * 276 + k];
            else if (n >= 112 && n < 176) v = w1v[(n - 112) * 276 + k];
        }
    } else {
        int ii = i - DEXT_SHORTS - W1_SHORTS;
        int e = ii & 7, lane = (ii >> 3) & 63, tc = ii >> 9; // tc = nt*4+kc
        int n = (tc >> 2) * 16 + (lane & 15);
        int k = (tc & 3) * 32 + (lane >> 4) * 8 + e;
        if (k < 100) v = w2a[n * 100 + k];
    }
    ws[i] = f2bf(v);
}

// ---- main fused kernel: 64 rows/block, NO runtime-indexed register arrays ----
__global__ __launch_bounds__(384) void net_v3(
    const float* __restrict__ state,
    const float* __restrict__ b1a, const float* __restrict__ b2a,
    const float* __restrict__ b1v, const float* __restrict__ w2v,
    const float* __restrict__ b2v,
    const short* __restrict__ ws, float* __restrict__ out, int Btot)
{
    __shared__ __align__(16) unsigned char smem[56320];
    short* xt   = (short*)smem;                 // [64][296] bf16 features (P1->P2)
    float* zl   = (float*)smem;                 // [64][68] f32 logits (P3->P4, aliases dead xt)
    short* ay   = (short*)(smem + 37888);       // [64][136]: state stage (P0->P1), y (P2->P3)
    float* valp = (float*)(smem + 55296);       // [4][64] val partials

    const int tid  = threadIdx.x;
    const int w    = tid >> 6;      // wave 0..5
    const int l    = tid & 63;
    const int lrow = l & 15;
    const int lk   = l >> 4;
    const int bg0  = blockIdx.x * 64;

    // ---- P0: stage state (64 rows x 128 f32 = 32 KB) -> ay bf16, fully coalesced ----
    {
        const float* sp = state + (size_t)bg0 * 128;
        #pragma unroll
        for (int it = 0; it < 6; ++it) {
            int t = tid + it * 384;             // f32x4 index, < 2048
            if (t < 2048) {
                f32x4 v4 = *(const f32x4*)(sp + t * 4);
                int f = t * 4, row = f >> 7, col = f & 127;
                short* dst = ay + row * AY_S + col;
                dst[0] = f2bf(v4[0]); dst[1] = f2bf(v4[1]);
                dst[2] = f2bf(v4[2]); dst[3] = f2bf(v4[3]);
            }
        }
    }
    // conv B-frags (3 n-tiles per wave), issued before barrier to overlap latency
    bf16x8 dx0[4], dx1[4], dx2[4];
    #pragma unroll
    for (int kc = 0; kc < 4; ++kc) {
        dx0[kc] = *(const bf16x8*)(ws + (((w     ) * 4 + kc) * 64 + l) * 8);
        dx1[kc] = *(const bf16x8*)(ws + (((w +  6) * 4 + kc) * 64 + l) * 8);
        dx2[kc] = *(const bf16x8*)(ws + (((w + 12) * 4 + kc) * 64 + l) * 8);
    }
    __syncthreads();

    // ---- P1: conv-GEMM  S[64,128] @ Dext[128,288] -> relu -> xt ----
    {
        f32x4 c0[4], c1[4], c2[4];
        #pragma unroll
        for (int mt = 0; mt < 4; ++mt) {
            c0[mt] = (f32x4){0.f,0.f,0.f,0.f};
            c1[mt] = (f32x4){0.f,0.f,0.f,0.f};
            c2[mt] = (f32x4){0.f,0.f,0.f,0.f};
        }
        #pragma unroll
        for (int mt = 0; mt < 4; ++mt) {
            bf16x8 a[4];
            #pragma unroll
            for (int kc = 0; kc < 4; ++kc)
                a[kc] = *(const bf16x8*)(ay + (mt * 16 + lrow) * AY_S + kc * 32 + lk * 8);
            #pragma unroll
            for (int kc = 0; kc < 4; ++kc) {
                c0[mt] = __builtin_amdgcn_mfma_f32_16x16x32_bf16(a[kc], dx0[kc], c0[mt], 0, 0, 0);
                c1[mt] = __builtin_amdgcn_mfma_f32_16x16x32_bf16(a[kc], dx1[kc], c1[mt], 0, 0, 0);
                c2[mt] = __builtin_amdgcn_mfma_f32_16x16x32_bf16(a[kc], dx2[kc], c2[mt], 0, 0, 0);
            }
        }
        #pragma unroll
        for (int mt = 0; mt < 4; ++mt)
            #pragma unroll
            for (int r = 0; r < 4; ++r) {
                short* xr = xt + (mt * 16 + lk * 4 + r) * XT_S + lrow;
                xr[(w     ) * 16] = f2bf(fmaxf(c0[mt][r], 0.f));
                xr[(w +  6) * 16] = f2bf(fmaxf(c1[mt][r], 0.f));
                xr[(w + 12) * 16] = f2bf(fmaxf(c2[mt][r], 0.f));
            }
    }
    // GEMM1 B-frags (overlap with barrier). Tile A: nt=w (0..5). Tile B: nt=w+6 (w<5 only).
    const bool haveB = (w < 5);
    bf16x8 bfA[9], bfB[9];
    #pragma unroll
    for (int kc = 0; kc < 9; ++kc)
        bfA[kc] = *(const bf16x8*)(ws + DEXT_SHORTS + ((w * 9 + kc) * 64 + l) * 8);
    if (haveB) {
        #pragma unroll
        for (int kc = 0; kc < 9; ++kc)
            bfB[kc] = *(const bf16x8*)(ws + DEXT_SHORTS + (((w + 6) * 9 + kc) * 64 + l) * 8);
    }
    float epbA, epbB = 0.f, epwB = 0.f;
    { const int colA = w * 16 + lrow; epbA = (colA < 100) ? b1a[colA] : 0.f; }
    if (haveB) {
        const int colB = (w + 6) * 16 + lrow;
        if (w == 0) epbB = (colB < 100) ? b1a[colB] : 0.f;     // nt=6: act tile
        else { epbB = b1v[colB - 112]; epwB = w2v[colB - 112]; } // nt=7..10: val tile
    }
    __syncthreads();

    // ---- P2: GEMM1  x[64,288] @ W1[288,176] ----
    {
        f32x4 accA[4], accB[4];
        #pragma unroll
        for (int mt = 0; mt < 4; ++mt) {
            accA[mt] = (f32x4){0.f,0.f,0.f,0.f};
            accB[mt] = (f32x4){0.f,0.f,0.f,0.f};
        }
        #pragma unroll
        for (int mt = 0; mt < 4; ++mt) {
            bf16x8 a[9];
            #pragma unroll
            for (int kc = 0; kc < 9; ++kc)
                a[kc] = *(const bf16x8*)(xt + (mt * 16 + lrow) * XT_S + kc * 32 + lk * 8);
            #pragma unroll
            for (int kc = 0; kc < 9; ++kc)
                accA[mt] = __builtin_amdgcn_mfma_f32_16x16x32_bf16(a[kc], bfA[kc], accA[mt], 0, 0, 0);
            if (haveB) {
                #pragma unroll
                for (int kc = 0; kc < 9; ++kc)
                    accB[mt] = __builtin_amdgcn_mfma_f32_16x16x32_bf16(a[kc], bfB[kc], accB[mt], 0, 0, 0);
            }
        }
        // epilogue tile A (always act: nt=w<=5): y cols w*16+lrow (0..95)
        #pragma unroll
        for (int mt = 0; mt < 4; ++mt)
            #pragma unroll
            for (int r = 0; r < 4; ++r) {
                float v = fmaxf(accA[mt][r] + epbA, 0.f);
                ay[(mt * 16 + lk * 4 + r) * AY_S + w * 16 + lrow] = f2bf(v);
            }
        if (haveB) {
            if (w == 0) {   // nt=6: act cols 96..111, plus zero K-pad cols 112..127
                #pragma unroll
                for (int mt = 0; mt < 4; ++mt)
                    #pragma unroll
                    for (int r = 0; r < 4; ++r) {
                        const int row = mt * 16 + lk * 4 + r;
                        float v = fmaxf(accB[mt][r] + epbB, 0.f);
                        ay[row * AY_S +  96 + lrow] = f2bf(v);
                        ay[row * AY_S + 112 + lrow] = 0;
                    }
            } else {        // nt=7..10: val tiles -> reduce over 16 cols -> valp
                #pragma unroll
                for (int mt = 0; mt < 4; ++mt)
                    #pragma unroll
                    for (int r = 0; r < 4; ++r) {
                        float v = fmaxf(accB[mt][r] + epbB, 0.f) * epwB;
                        v += __shfl_xor(v, 1); v += __shfl_xor(v, 2);
                        v += __shfl_xor(v, 4); v += __shfl_xor(v, 8);
                        if (lrow == 0) valp[(w - 1) * 64 + mt * 16 + lk * 4 + r] = v;
                    }
            }
        }
    }
    // GEMM2 B-frags (overlap with barrier)
    bf16x8 b2f[4];
    float bias2 = 0.f;
    if (w < 4) {
        #pragma unroll
        for (int kc = 0; kc < 4; ++kc)
            b2f[kc] = *(const bf16x8*)(ws + DEXT_SHORTS + W1_SHORTS + ((w * 4 + kc) * 64 + l) * 8);
        bias2 = b2a[w * 16 + lrow];
    }
    __syncthreads();

    // ---- P3: GEMM2 y[64,128] @ W2[128,64] (waves 0-3) -> zl; wave 5: tanh(val) ----
    if (w < 4) {
        f32x4 acc2[4];
        #pragma unroll
        for (int mt = 0; mt < 4; ++mt) acc2[mt] = (f32x4){0.f,0.f,0.f,0.f};
        #pragma unroll
        for (int mt = 0; mt < 4; ++mt)
            #pragma unroll
            for (int kc = 0; kc < 4; ++kc) {
                bf16x8 a2 = *(const bf16x8*)(ay + (mt * 16 + lrow) * AY_S + kc * 32 + lk * 8);
                acc2[mt] = __builtin_amdgcn_mfma_f32_16x16x32_bf16(a2, b2f[kc], acc2[mt], 0, 0, 0);
            }
        #pragma unroll
        for (int mt = 0; mt < 4; ++mt)
            #pragma unroll
            for (int r = 0; r < 4; ++r)
                zl[(mt * 16 + lk * 4 + r) * ZL_S + w * 16 + lrow] = acc2[mt][r] + bias2;
    } else if (w == 5) {
        float v = valp[l] + valp[64 + l] + valp[128 + l] + valp[192 + l] + b2v[0];
        out[(size_t)Btot * 64 + bg0 + l] = tanhf(v);
    }
    __syncthreads();

    // ---- P4: log-softmax, 4 lanes/row; each (c,q-group) store = one full 64B line ----
    if (w < 4) {
        const int rl = l >> 2, q = l & 3;
        const int row = w * 16 + rl;
        const float* zr = zl + row * ZL_S;
        f32x4 v[4];
        float m = -1e30f;
        #pragma unroll
        for (int c = 0; c < 4; ++c) {
            v[c] = *(const f32x4*)(zr + c * 16 + q * 4);
            m = fmaxf(m, fmaxf(fmaxf(v[c][0], v[c][1]), fmaxf(v[c][2], v[c][3])));
        }
        m = fmaxf(m, __shfl_xor(m, 1));
        m = fmaxf(m, __shfl_xor(m, 2));
        float s = 0.f;
        #pragma unroll
        for (int c = 0; c < 4; ++c)
            #pragma unroll
            for (int e = 0; e < 4; ++e) s += __expf(v[c][e] - m);
        s += __shfl_xor(s, 1);
        s += __shfl_xor(s, 2);
        const float lsm = m + __logf(s);
        float* o = out + (size_t)(bg0 + row) * 64;
        #pragma unroll
        for (int c = 0; c < 4; ++c) {
            f32x4 ov;
            #pragma unroll
            for (int e = 0; e < 4; ++e) ov[e] = v[c][e] - lsm;
            *(f32x4*)(o + c * 16 + q * 4) = ov;
        }
    }
}

// ---- fallback (ws too small): weights straight from global, de-scratched similarly ----
__global__ __launch_bounds__(384) void net_v1(
    const float* __restrict__ state,
    const float* __restrict__ myp,  const float* __restrict__ hisp,
    const float* __restrict__ w1a,  const float* __restrict__ b1a,
    const float* __restrict__ w2a,  const float* __restrict__ b2a,
    const float* __restrict__ w1v,  const float* __restrict__ b1v,
    const float* __restrict__ w2v,  const float* __restrict__ b2v,
    float* __restrict__ out, int Btot)
{
    __shared__ __align__(16) unsigned char smem[56320];
    short* xt   = (short*)smem;
    float* zl   = (float*)smem;
    short* ay   = (short*)(smem + 37888);
    float* valp = (float*)(smem + 55296);
    const int tid = threadIdx.x, w = tid >> 6, l = tid & 63, lrow = l & 15, lk = l >> 4;
    const int bg0 = blockIdx.x * 64;
    const bool haveB = (w < 5);

    // scalar conv path (lane = row), wave = (p,j)
    const int cp = (w >= 3) ? 1 : 0, cj = (w >= 3) ? (w - 3) : w;
    float prm[10];
    { const float* ps = (cp == 0 ? myp : hisp) + cj * 10;
      #pragma unroll
      for (int i = 0; i < 10; i++) prm[i] = ps[i]; }
    // zero xt (pads)
    for (int i = tid; i < 9472; i += 384) ((unsigned*)xt)[i] = 0u;
    __syncthreads();
    {
        float racc[8], cacc[8], macc[15], aacc[15];
        #pragma unroll
        for (int i = 0; i < 8; i++) { racc[i] = 0.f; cacc[i] = 0.f; }
        #pragma unroll
        for (int i = 0; i < 15; i++) { macc[i] = 0.f; aacc[i] = 0.f; }
        const float* S = state + ((size_t)(bg0 + l) * 2 + cp) * 64;
        #pragma unroll
        for (int x = 0; x < 8; x++) {
            f32x4 lo = *(const f32x4*)(S + x * 8);
            f32x4 hi = *(const f32x4*)(S + x * 8 + 4);
            #pragma unroll
            for (int y = 0; y < 8; y++) {
                float s = (y < 4) ? lo[y] : hi[y - 4];
                float t = s * prm[m8(x, y)];
                racc[x] += t; cacc[y] += t;
                macc[(y >= x) ? (y - x) : (x - y + 7)] += t;
                aacc[x + y] += t;
            }
        }
        short* xr = xt + l * XT_S;
        #pragma unroll
        for (int i = 0; i < 8; i++)  xr[(cj * 8 + i) * 2 + cp]        = f2bf(fmaxf(racc[i], 0.f));
        #pragma unroll
        for (int i = 0; i < 8; i++)  xr[48 + (cj * 8 + i) * 2 + cp]   = f2bf(fmaxf(cacc[i], 0.f));
        #pragma unroll
        for (int k = 0; k < 15; k++) xr[96 + (cj * 15 + k) * 2 + cp]  = f2bf(fmaxf(macc[k], 0.f));
        #pragma unroll
        for (int k = 0; k < 15; k++) xr[186 + (cj * 15 + k) * 2 + cp] = f2bf(fmaxf(aacc[k], 0.f));
    }
    bf16x8 bfA[9], bfB[9];
    {
        const int nA = w * 16 + lrow;
        const float* srcA = (nA < 100) ? (w1a + (size_t)nA * 276) : w1a;
        #pragma unroll
        for (int kc = 0; kc < 9; kc++) {
            bf16x8 r;
            #pragma unroll
            for (int e = 0; e < 8; e++) {
                int k = kc * 32 + lk * 8 + e;
                bool ok = (nA < 100) && (k < 276);
                r[e] = f2bf(ok ? srcA[k] : 0.f);
            }
            bfA[kc] = r;
        }
        if (haveB) {
            const int nB = (w + 6) * 16 + lrow;
            const float* srcB; bool validB;
            if (nB < 100)       { srcB = w1a + (size_t)nB * 276;         validB = true; }
            else if (nB >= 112) { srcB = w1v + (size_t)(nB - 112) * 276; validB = true; }
            else                { srcB = w1a;                            validB = false; }
            #pragma unroll
            for (int kc = 0; kc < 9; kc++) {
                bf16x8 r;
                #pragma unroll
                for (int e = 0; e < 8; e++) {
                    int k = kc * 32 + lk * 8 + e;
                    bool ok = validB && (k < 276);
                    r[e] = f2bf(ok ? srcB[k] : 0.f);
                }
                bfB[kc] = r;
            }
        }
    }
    float epbA, epbB = 0.f, epwB = 0.f;
    { const int colA = w * 16 + lrow; epbA = (colA < 100) ? b1a[colA] : 0.f; }
    if (haveB) {
        const int colB = (w + 6) * 16 + lrow;
        if (w == 0) epbB = (colB < 100) ? b1a[colB] : 0.f;
        else { epbB = b1v[colB - 112]; epwB = w2v[colB - 112]; }
    }
    __syncthreads();
    {
        f32x4 accA[4], accB[4];
        #pragma unroll
        for (int mt = 0; mt < 4; ++mt) {
            accA[mt] = (f32x4){0.f,0.f,0.f,0.f};
            accB[mt] = (f32x4){0.f,0.f,0.f,0.f};
        }
        #pragma unroll
        for (int mt = 0; mt < 4; ++mt) {
            bf16x8 a[9];
            #pragma unroll
            for (int kc = 0; kc < 9; ++kc)
                a[kc] = *(const bf16x8*)(xt + (mt * 16 + lrow) * XT_S + kc * 32 + lk * 8);
            #pragma unroll
            for (int kc = 0; kc < 9; ++kc)
                accA[mt] = __builtin_amdgcn_mfma_f32_16x16x32_bf16(a[kc], bfA[kc], accA[mt], 0, 0, 0);
            if (haveB) {
                #pragma unroll
                for (int kc = 0; kc < 9; ++kc)
                    accB[mt] = __builtin_amdgcn_mfma_f32_16x16x32_bf16(a[kc], bfB[kc], accB[mt], 0, 0, 0);
            }
        }
        #pragma unroll
        for (int mt = 0; mt < 4; ++mt)
            #pragma unroll
            for (int r = 0; r < 4; ++r) {
                float v = fmaxf(accA[mt][r] + epbA, 0.f);
                ay[(mt * 16 + lk * 4 + r) * AY_S + w * 16 + lrow] = f2bf(v);
            }
        if (haveB) {
            if (w == 0) {
                #pragma unroll
                for (int mt = 0; mt < 4; ++mt)
                    #pragma unroll
                    for (int r = 0; r < 4; ++r) {
                        const int row = mt * 16 + lk * 4 + r;
                        float v = fmaxf(accB[mt][r] + epbB, 0.f);
                        ay[row * AY_S +  96 + lrow] = f2bf(v);
                        ay[row * AY_S + 112 + lrow] = 0;
                    }
            } else {
                #pragma unroll
                for (int mt = 0; mt < 4; ++mt)
                    #pragma unroll
                    for (int r = 0; r < 4; ++r) {
                        float v = fmaxf(accB[mt][r] + epbB, 0.f) * epwB;
                        v += __shfl_xor(v, 1); v += __shfl_xor(v, 2);
                        v += __shfl_xor(v, 4); v += __shfl_xor(v, 8);
                        if (lrow == 0) valp[(w - 1) * 64 + mt * 16 + lk * 4 + r] = v;
                    }
            }
        }
    }
    bf16x8 b2f[4];
    float bias2 = 0.f;
    if (w < 4) {
        const float* src2 = w2a + (size_t)(w * 16 + lrow) * 100;
        #pragma unroll
        for (int kc = 0; kc < 4; kc++) {
            bf16x8 r;
            #pragma unroll
            for (int e = 0; e < 8; e++) { int k = kc * 32 + lk * 8 + e; r[e] = f2bf((k < 100) ? src2[k] : 0.f); }
            b2f[kc] = r;
        }
        bias2 = b2a[w * 16 + lrow];
    }
    __syncthreads();
    if (w < 4) {
        f32x4 acc2[4];
        #pragma unroll
        for (int mt = 0; mt < 4; ++mt) acc2[mt] = (f32x4){0.f,0.f,0.f,0.f};
        #pragma unroll
        for (int mt = 0; mt < 4; ++mt)
            #pragma unroll
            for (int kc = 0; kc < 4; ++kc) {
                bf16x8 a2 = *(const bf16x8*)(ay + (mt * 16 + lrow) * AY_S + kc * 32 + lk * 8);
                acc2[mt] = __builtin_amdgcn_mfma_f32_16x16x32_bf16(a2, b2f[kc], acc2[mt], 0, 0, 0);
            }
        #pragma unroll
        for (int mt = 0; mt < 4; ++mt)
            #pragma unroll
            for (int r = 0; r < 4; ++r)
                zl[(mt * 16 + lk * 4 + r) * ZL_S + w * 16 + lrow] = acc2[mt][r] + bias2;
    } else if (w == 5) {
        float v = valp[l] + valp[64 + l] + valp[128 + l] + valp[192 + l] + b2v[0];
        out[(size_t)Btot * 64 + bg0 + l] = tanhf(v);
    }
    __syncthreads();
    if (w < 4) {
        const int rl = l >> 2, q = l & 3;
        const int row = w * 16 + rl;
        const float* zr = zl + row * ZL_S;
        f32x4 v[4]; float m = -1e30f;
        #pragma unroll
        for (int c = 0; c < 4; ++c) {
            v[c] = *(const f32x4*)(zr + c * 16 + q * 4);
            m = fmaxf(m, fmaxf(fmaxf(v[c][0], v[c][1]), fmaxf(v[c][2], v[c][3])));
        }
        m = fmaxf(m, __shfl_xor(m, 1));
        m = fmaxf(m, __shfl_xor(m, 2));
        float s = 0.f;
        #pragma unroll
        for (int c = 0; c < 4; ++c)
            #pragma unroll
            for (int e = 0; e < 4; ++e) s += __expf(v[c][e] - m);
        s += __shfl_xor(s, 1);
        s += __shfl_xor(s, 2);
        const float lsm = m + __logf(s);
        float* o = out + (size_t)(bg0 + row) * 64;
        #pragma unroll
        for (int c = 0; c < 4; ++c) {
            f32x4 ov;
            #pragma unroll
            for (int e = 0; e < 4; ++e) ov[e] = v[c][e] - lsm;
            *(f32x4*)(o + c * 16 + q * 4) = ov;
        }
    }
}

extern "C" void kernel_launch(void* const* d_in, const int* in_sizes, int n_in,
                              void* d_out, int out_size, void* d_ws, size_t ws_size,
                              hipStream_t stream) {
    const float* state = (const float*)d_in[0];
    const float* myp   = (const float*)d_in[1];
    const float* hisp  = (const float*)d_in[2];
    const float* w1a   = (const float*)d_in[3];
    const float* b1a   = (const float*)d_in[4];
    const float* w2a   = (const float*)d_in[5];
    const float* b2a   = (const float*)d_in[6];
    const float* w1v   = (const float*)d_in[7];
    const float* b1v   = (const float*)d_in[8];
    const float* w2v   = (const float*)d_in[9];
    const float* b2v   = (const float*)d_in[10];
    float* out = (float*)d_out;
    const int Btot = in_sizes[0] / 128;          // (B,2,8,8)
    const int blocks = Btot / 64;
    if (ws_size >= (size_t)WS2_SHORTS * sizeof(short)) {
        short* ws = (short*)d_ws;
        prep2<<<dim3((WS2_SHORTS + 255) / 256), dim3(256), 0, stream>>>(myp, hisp, w1a, w1v, w2a, ws);
        net_v3<<<dim3(blocks), dim3(384), 0, stream>>>(
            state, b1a, b2a, b1v, w2v, b2v, ws, out, Btot);
    } else {
        net_v1<<<dim3(blocks), dim3(384), 0, stream>>>(
            state, myp, hisp, w1a, b1a, w2a, b2a, w1v, b1v, w2v, b2v, out, Btot);
    }
}